// Round 3
// baseline (225.728 us; speedup 1.0000x reference)
//
#include <hip/hip_runtime.h>
#include <stdint.h>
#include <stddef.h>

#define SEQ 4096
#define DIM 1024

typedef __bf16 bf16x8 __attribute__((ext_vector_type(8)));
typedef float floatx4 __attribute__((ext_vector_type(4)));
typedef float floatx16 __attribute__((ext_vector_type(16)));
typedef unsigned short u16x8 __attribute__((ext_vector_type(8)));

__device__ __forceinline__ unsigned short f2b(float f) {
  union { float f; unsigned u; } v; v.f = f;
  unsigned u = v.u;
  unsigned r = (u + 0x7FFFu + ((u >> 16) & 1u)) >> 16;
  return (unsigned short)r;
}
__device__ __forceinline__ float b2f(unsigned short h) {
  union { unsigned u; float f; } v; v.u = ((unsigned)h) << 16;
  return v.f;
}

// ---------------- fused fp32 -> bf16 convert (x, wq, wk, wv in one launch) --------
__global__ __launch_bounds__(256)
void cvt_all(const float* __restrict__ x, const float* __restrict__ wq,
             const float* __restrict__ wk, const float* __restrict__ wv,
             unsigned short* __restrict__ xb, unsigned short* __restrict__ wqb,
             unsigned short* __restrict__ wkb, unsigned short* __restrict__ wvb) {
  const int bid = blockIdx.x;
  const float* src;
  unsigned short* dst;
  int off;
  if (bid < 4096)      { src = x;  dst = xb;  off = bid; }
  else if (bid < 5120) { src = wq; dst = wqb; off = bid - 4096; }
  else if (bid < 6144) { src = wk; dst = wkb; off = bid - 5120; }
  else                 { src = wv; dst = wvb; off = bid - 6144; }
  const int i = off * 1024 + threadIdx.x * 4;
  float4 f = *(const float4*)(src + i);
  ushort4 o;
  o.x = f2b(f.x); o.y = f2b(f.y); o.z = f2b(f.z); o.w = f2b(f.w);
  *(ushort4*)(dst + i) = o;
}

// ---------------- supertile swizzle for L2 locality ----------------
// gx = gridDim.x (N-tiles), gy = gridDim.y (M-tiles). 8 consecutive blocks
// walk M within a group sharing one B-tile; groups of 8 M-rows stay L2-hot.
__device__ __forceinline__ void swizzle_tiles(int gx, int gy, int& bx, int& by) {
  const int pid = blockIdx.y * gx + blockIdx.x;
  const int GM = 8;
  const int group = pid / (GM * gx);
  const int first = group * GM;
  const int gsz = (gy - first) < GM ? (gy - first) : GM;
  by = first + (pid % gsz);
  bx = (pid % (GM * gx)) / gsz;
}

// ---------------- core 128x128 B^T-form bf16 tile GEMM (32x32x16 MFMA) ------------
// C_tile[128,128] += A[tile_m:+128, :kext] * B[tile_n:+128, :kext]^T
// LDS XOR-swizzled: granule g (8 elts) of row r stored at slot g^(r&7).
// Writer swizzles the SOURCE column (global_load_lds dest is lane-ordered).
// Wave tile 64x64 = 2x2 of 32x32 MFMA tiles.
// A-frag (32x32x16): row = lane&31, k = (lane>>5)*8 .. +8 (bf16x8). B analog.
__device__ __forceinline__ void gemm_core(
    const unsigned short* __restrict__ A,
    const unsigned short* __restrict__ B,
    int lda, int ldb, int kext,
    unsigned short* As, unsigned short* Bs,
    floatx16 acc[2][2]) {
  const int tid  = threadIdx.x;
  const int lane = tid & 63;
  const int wave = tid >> 6;
  const int sub_m = (wave >> 1) * 64;
  const int sub_n = (wave & 1) * 64;
  const int r31   = lane & 31;
  const int khalf = lane >> 5;

  const int srow  = tid >> 3;                  // 0..31 (row within 32-row step)
  const int sgran = (tid & 7) ^ (srow & 7);    // swizzled source granule
  const int scol  = sgran * 8;
  const int dflat = tid * 8;                   // LDS dest (lane-ordered, fixed)

  const unsigned short* Ag = A + (size_t)srow * lda + scol;
  const unsigned short* Bg = B + (size_t)srow * ldb + scol;

  for (int k0 = 0; k0 < kext; k0 += 64) {
    __syncthreads();   // previous iteration's readers done before overwrite
#pragma unroll
    for (int j = 0; j < 4; j++) {
      __builtin_amdgcn_global_load_lds(
          (const __attribute__((address_space(1))) void*)(Ag + (size_t)(j * 32) * lda + k0),
          (__attribute__((address_space(3))) void*)(&As[j * 2048 + dflat]), 16, 0, 0);
      __builtin_amdgcn_global_load_lds(
          (const __attribute__((address_space(1))) void*)(Bg + (size_t)(j * 32) * ldb + k0),
          (__attribute__((address_space(3))) void*)(&Bs[j * 2048 + dflat]), 16, 0, 0);
    }
    __syncthreads();   // drains vmcnt + makes LDS visible
#pragma unroll
    for (int ks = 0; ks < 64; ks += 16) {
      const int g = (ks >> 3) + khalf;
      bf16x8 af[2], bfr[2];
#pragma unroll
      for (int i = 0; i < 2; i++) {
        const int R = sub_m + 32 * i + r31;
        af[i] = *(const bf16x8*)&As[R * 64 + (g ^ (R & 7)) * 8];
      }
#pragma unroll
      for (int j = 0; j < 2; j++) {
        const int R = sub_n + 32 * j + r31;
        bfr[j] = *(const bf16x8*)&Bs[R * 64 + (g ^ (R & 7)) * 8];
      }
#pragma unroll
      for (int i = 0; i < 2; i++)
#pragma unroll
        for (int j = 0; j < 2; j++)
          acc[i][j] = __builtin_amdgcn_mfma_f32_32x32x16_bf16(af[i], bfr[j],
                                                              acc[i][j], 0, 0, 0);
    }
  }
}

// C/D layout (32x32): col = lane&31, row = (reg&3) + 8*(reg>>2) + 4*(lane>>5)
// [verified m74/m101]

// ---------------- fused QKV: z=0 Q, z=1 K, z=2 V(transposed store) ----------------
__global__ __launch_bounds__(256, 2)
void qkv_gemm(const unsigned short* __restrict__ xb,
              const unsigned short* __restrict__ wqb,
              const unsigned short* __restrict__ wkb,
              const unsigned short* __restrict__ wvb,
              const float* __restrict__ bq, const float* __restrict__ bk,
              const float* __restrict__ bv,
              unsigned short* __restrict__ qb, unsigned short* __restrict__ kb,
              unsigned short* __restrict__ vtb) {
  __shared__ unsigned short As[8192];
  __shared__ unsigned short Bs[8192];
  const int z = blockIdx.z;
  const unsigned short* W = (z == 0) ? wqb : (z == 1) ? wkb : wvb;
  const float* bias = (z == 0) ? bq : (z == 1) ? bk : bv;
  int bx, by;
  swizzle_tiles(gridDim.x, gridDim.y, bx, by);
  const int tile_m = by * 128;
  const int tile_n = bx * 128;

  floatx16 acc[2][2];
#pragma unroll
  for (int i = 0; i < 2; i++)
#pragma unroll
    for (int j = 0; j < 2; j++) acc[i][j] = (floatx16)0.0f;

  gemm_core(xb + (size_t)tile_m * DIM, W + (size_t)tile_n * DIM,
            DIM, DIM, DIM, As, Bs, acc);

  const int lane = threadIdx.x & 63;
  const int wave = threadIdx.x >> 6;
  const int sub_m = (wave >> 1) * 64;
  const int sub_n = (wave & 1) * 64;
  const int r31 = lane & 31;
  const int rowoff = 4 * (lane >> 5);

  float biasv[2];
#pragma unroll
  for (int j = 0; j < 2; j++) biasv[j] = bias[tile_n + sub_n + 32 * j + r31];

  unsigned short* outp = (z == 0) ? qb : kb;
#pragma unroll
  for (int i = 0; i < 2; i++) {
#pragma unroll
    for (int j = 0; j < 2; j++) {
#pragma unroll
      for (int r = 0; r < 16; r++) {
        const int m = tile_m + sub_m + 32 * i + (r & 3) + 8 * (r >> 2) + rowoff;
        const int n = tile_n + sub_n + 32 * j + r31;
        const unsigned short v = f2b(acc[i][j][r] + biasv[j]);
        if (z < 2)
          outp[(size_t)m * DIM + n] = v;
        else
          vtb[(size_t)n * SEQ + m] = v;   // V^T [DIM, SEQ]
      }
    }
  }
}

// ---------------- scores = (Q K^T) * scale, bf16 out ----------------
__global__ __launch_bounds__(256, 2)
void score_gemm(const unsigned short* __restrict__ qb,
                const unsigned short* __restrict__ kb,
                unsigned short* __restrict__ sc, float scale) {
  __shared__ unsigned short As[8192];
  __shared__ unsigned short Bs[8192];
  int bx, by;
  swizzle_tiles(gridDim.x, gridDim.y, bx, by);
  const int tile_m = by * 128;
  const int tile_n = bx * 128;

  floatx16 acc[2][2];
#pragma unroll
  for (int i = 0; i < 2; i++)
#pragma unroll
    for (int j = 0; j < 2; j++) acc[i][j] = (floatx16)0.0f;

  gemm_core(qb + (size_t)tile_m * DIM, kb + (size_t)tile_n * DIM,
            DIM, DIM, DIM, As, Bs, acc);

  const int lane = threadIdx.x & 63;
  const int wave = threadIdx.x >> 6;
  const int sub_m = (wave >> 1) * 64;
  const int sub_n = (wave & 1) * 64;
  const int r31 = lane & 31;
  const int rowoff = 4 * (lane >> 5);
#pragma unroll
  for (int i = 0; i < 2; i++) {
#pragma unroll
    for (int j = 0; j < 2; j++) {
#pragma unroll
      for (int r = 0; r < 16; r++) {
        const int m = tile_m + sub_m + 32 * i + (r & 3) + 8 * (r >> 2) + rowoff;
        const int n = tile_n + sub_n + 32 * j + r31;
        sc[(size_t)m * SEQ + n] = f2b(acc[i][j][r] * scale);
      }
    }
  }
}

// ---------------- PV split-K=2: z=0 -> d_out, z=1 -> partial ----------------
__global__ __launch_bounds__(256, 2)
void pv_gemm(const unsigned short* __restrict__ sc,
             const unsigned short* __restrict__ vtb,
             float* __restrict__ out0, float* __restrict__ out1) {
  __shared__ unsigned short As[8192];
  __shared__ unsigned short Bs[8192];
  const int z = blockIdx.z;
  const int koff = z * (SEQ / 2);
  float* C = z ? out1 : out0;
  int bx, by;
  swizzle_tiles(gridDim.x, gridDim.y, bx, by);
  const int tile_m = by * 128;
  const int tile_n = bx * 128;

  floatx16 acc[2][2];
#pragma unroll
  for (int i = 0; i < 2; i++)
#pragma unroll
    for (int j = 0; j < 2; j++) acc[i][j] = (floatx16)0.0f;

  gemm_core(sc + (size_t)tile_m * SEQ + koff,
            vtb + (size_t)tile_n * SEQ + koff,
            SEQ, SEQ, SEQ / 2, As, Bs, acc);

  const int lane = threadIdx.x & 63;
  const int wave = threadIdx.x >> 6;
  const int sub_m = (wave >> 1) * 64;
  const int sub_n = (wave & 1) * 64;
  const int r31 = lane & 31;
  const int rowoff = 4 * (lane >> 5);
#pragma unroll
  for (int i = 0; i < 2; i++) {
#pragma unroll
    for (int j = 0; j < 2; j++) {
#pragma unroll
      for (int r = 0; r < 16; r++) {
        const int m = tile_m + sub_m + 32 * i + (r & 3) + 8 * (r >> 2) + rowoff;
        const int n = tile_n + sub_n + 32 * j + r31;
        C[(size_t)m * DIM + n] = acc[i][j][r];
      }
    }
  }
}

// ---------------- out += partial ----------------
__global__ __launch_bounds__(256)
void reduce_add(float* __restrict__ out, const float* __restrict__ part) {
  const int i = (blockIdx.x * 256 + threadIdx.x) * 4;
  float4 a = *(const float4*)(out + i);
  float4 b = *(const float4*)(part + i);
  a.x += b.x; a.y += b.y; a.z += b.z; a.w += b.w;
  *(float4*)(out + i) = a;
}

// ---------------- in-place row softmax on bf16 [SEQ, SEQ] ----------------
__global__ __launch_bounds__(256)
void softmax_inplace(unsigned short* __restrict__ P) {
  const int row = blockIdx.x;
  unsigned short* p = P + (size_t)row * SEQ;
  const int tid  = threadIdx.x;
  const int lane = tid & 63;
  const int wave = tid >> 6;

  u16x8 raw0 = *(const u16x8*)(p + tid * 16);
  u16x8 raw1 = *(const u16x8*)(p + tid * 16 + 8);
  float v[16];
#pragma unroll
  for (int k = 0; k < 8; k++) v[k] = b2f(raw0[k]);
#pragma unroll
  for (int k = 0; k < 8; k++) v[8 + k] = b2f(raw1[k]);

  float mx = -1e30f;
#pragma unroll
  for (int k = 0; k < 16; k++) mx = fmaxf(mx, v[k]);
#pragma unroll
  for (int off = 32; off > 0; off >>= 1) mx = fmaxf(mx, __shfl_xor(mx, off, 64));
  __shared__ float redm[4];
  __shared__ float reds[4];
  if (lane == 0) redm[wave] = mx;
  __syncthreads();
  mx = fmaxf(fmaxf(redm[0], redm[1]), fmaxf(redm[2], redm[3]));

  float sum = 0.0f;
#pragma unroll
  for (int k = 0; k < 16; k++) {
    v[k] = exp2f((v[k] - mx) * 1.44269504f);
    sum += v[k];
  }
#pragma unroll
  for (int off = 32; off > 0; off >>= 1) sum += __shfl_xor(sum, off, 64);
  if (lane == 0) reds[wave] = sum;
  __syncthreads();
  sum = reds[0] + reds[1] + reds[2] + reds[3];
  const float inv = 1.0f / sum;

  u16x8 o0, o1;
#pragma unroll
  for (int k = 0; k < 8; k++) o0[k] = f2b(v[k] * inv);
#pragma unroll
  for (int k = 0; k < 8; k++) o1[k] = f2b(v[8 + k] * inv);
  *(u16x8*)(p + tid * 16) = o0;
  *(u16x8*)(p + tid * 16 + 8) = o1;
}

extern "C" void kernel_launch(void* const* d_in, const int* in_sizes, int n_in,
                              void* d_out, int out_size, void* d_ws, size_t ws_size,
                              hipStream_t stream) {
  const float* x  = (const float*)d_in[0];
  const float* wq = (const float*)d_in[1];
  const float* bq = (const float*)d_in[2];
  const float* wk = (const float*)d_in[3];
  const float* bk = (const float*)d_in[4];
  const float* wv = (const float*)d_in[5];
  const float* bv = (const float*)d_in[6];

  uint8_t* ws = (uint8_t*)d_ws;
  // workspace layout (70 MiB total; `part` aliases the region dead by PV time)
  unsigned short* xb  = (unsigned short*)(ws);                      // [0,8)   MiB
  unsigned short* wqb = (unsigned short*)(ws + ((size_t)8  << 20)); // [8,10)
  unsigned short* wkb = (unsigned short*)(ws + ((size_t)10 << 20)); // [10,12)
  unsigned short* wvb = (unsigned short*)(ws + ((size_t)12 << 20)); // [12,14)
  unsigned short* qb  = (unsigned short*)(ws + ((size_t)14 << 20)); // [14,22)
  unsigned short* kb  = (unsigned short*)(ws + ((size_t)22 << 20)); // [22,30)
  unsigned short* vtb = (unsigned short*)(ws + ((size_t)30 << 20)); // [30,38)  V^T [DIM][SEQ]
  unsigned short* sc  = (unsigned short*)(ws + ((size_t)38 << 20)); // [38,70)  scores/attn
  float*          part = (float*)(ws);                              // [0,16)   PV k-chunk-1 partial

  // fp32 -> bf16 (x: 4096 blocks, each weight: 1024 blocks)
  cvt_all<<<7168, 256, 0, stream>>>(x, wq, wk, wv, xb, wqb, wkb, wvb);

  // fused Q/K/V^T projection (768 blocks -> 3 blocks/CU)
  qkv_gemm<<<dim3(DIM / 128, SEQ / 128, 3), 256, 0, stream>>>(
      xb, wqb, wkb, wvb, bq, bk, bv, qb, kb, vtb);

  // scores = (Q K^T) / sqrt(D)   (1024 blocks)
  score_gemm<<<dim3(SEQ / 128, SEQ / 128), 256, 0, stream>>>(qb, kb, sc, 0.03125f);

  // softmax rows in place
  softmax_inplace<<<SEQ, 256, 0, stream>>>(sc);

  // out = attn @ V, split-K=2 (512 blocks): chunk0 -> d_out, chunk1 -> part
  pv_gemm<<<dim3(DIM / 128, SEQ / 128, 2), 256, 0, stream>>>(
      sc, vtb, (float*)d_out, part);

  // d_out += part
  reduce_add<<<(SEQ * DIM) / 1024, 256, 0, stream>>>((float*)d_out, part);
}

// Round 4
// 223.849 us; speedup vs baseline: 1.0084x; 1.0084x over previous
//
#include <hip/hip_runtime.h>
#include <stdint.h>
#include <stddef.h>

#define SEQ 4096
#define DIM 1024

typedef __bf16 bf16x8 __attribute__((ext_vector_type(8)));
typedef float floatx4 __attribute__((ext_vector_type(4)));
typedef unsigned short u16x8 __attribute__((ext_vector_type(8)));

__device__ __forceinline__ unsigned short f2b(float f) {
  union { float f; unsigned u; } v; v.f = f;
  unsigned u = v.u;
  unsigned r = (u + 0x7FFFu + ((u >> 16) & 1u)) >> 16;
  return (unsigned short)r;
}
__device__ __forceinline__ float b2f(unsigned short h) {
  union { unsigned u; float f; } v; v.u = ((unsigned)h) << 16;
  return v.f;
}

// ---------------- fused fp32 -> bf16 convert (x, wq, wk, wv in one launch) --------
__global__ __launch_bounds__(256)
void cvt_all(const float* __restrict__ x, const float* __restrict__ wq,
             const float* __restrict__ wk, const float* __restrict__ wv,
             unsigned short* __restrict__ xb, unsigned short* __restrict__ wqb,
             unsigned short* __restrict__ wkb, unsigned short* __restrict__ wvb) {
  const int bid = blockIdx.x;
  const float* src;
  unsigned short* dst;
  int off;
  if (bid < 4096)      { src = x;  dst = xb;  off = bid; }
  else if (bid < 5120) { src = wq; dst = wqb; off = bid - 4096; }
  else if (bid < 6144) { src = wk; dst = wkb; off = bid - 5120; }
  else                 { src = wv; dst = wvb; off = bid - 6144; }
  const int i = off * 1024 + threadIdx.x * 4;
  float4 f = *(const float4*)(src + i);
  ushort4 o;
  o.x = f2b(f.x); o.y = f2b(f.y); o.z = f2b(f.z); o.w = f2b(f.w);
  *(ushort4*)(dst + i) = o;
}

// ---------------- supertile swizzle for L2 locality (square grids) ----------------
__device__ __forceinline__ void swizzle_tiles(int gx, int gy, int& bx, int& by) {
  const int pid = blockIdx.y * gx + blockIdx.x;
  const int GM = 8;
  const int group = pid / (GM * gx);
  const int first = group * GM;
  const int gsz = (gy - first) < GM ? (gy - first) : GM;
  by = first + (pid % gsz);
  bx = (pid % (GM * gx)) / gsz;
}

// ---------------- core 128x128 B^T-form bf16 GEMM (16x16x32 MFMA) ----------------
// C_tile[128,128] += A[0:128, :kext] * B[0:128, :kext]^T  (A,B pre-offset)
// LDS XOR-swizzle: granule g (8 elts) of row r at slot g^(r&7); writer swizzles
// the SOURCE column (global_load_lds dest is lane-ordered). Fragment read
// pattern (quad-rotated slot base) measured conflict-free in round 2;
// the 32x32 khalf pattern cost exactly 4 conflict-cycles per b128 — reverted.
__device__ __forceinline__ void gemm_core128(
    const unsigned short* __restrict__ A,
    const unsigned short* __restrict__ B,
    int lda, int ldb, int kext,
    unsigned short* As, unsigned short* Bs,
    floatx4 acc[4][4]) {
  const int tid  = threadIdx.x;
  const int lane = tid & 63;
  const int wave = tid >> 6;
  const int sub_m = (wave >> 1) * 64;
  const int sub_n = (wave & 1) * 64;
  const int col  = lane & 15;
  const int quad = lane >> 4;

  const int srow  = tid >> 3;
  const int sgran = (tid & 7) ^ (srow & 7);
  const int scol  = sgran * 8;
  const int dflat = tid * 8;

  const unsigned short* Ag = A + (size_t)srow * lda + scol;
  const unsigned short* Bg = B + (size_t)srow * ldb + scol;

  for (int k0 = 0; k0 < kext; k0 += 64) {
    __syncthreads();
#pragma unroll
    for (int j = 0; j < 4; j++) {
      __builtin_amdgcn_global_load_lds(
          (const __attribute__((address_space(1))) void*)(Ag + (size_t)(j * 32) * lda + k0),
          (__attribute__((address_space(3))) void*)(&As[j * 2048 + dflat]), 16, 0, 0);
      __builtin_amdgcn_global_load_lds(
          (const __attribute__((address_space(1))) void*)(Bg + (size_t)(j * 32) * ldb + k0),
          (__attribute__((address_space(3))) void*)(&Bs[j * 2048 + dflat]), 16, 0, 0);
    }
    __syncthreads();
#pragma unroll
    for (int ks = 0; ks < 64; ks += 32) {
      const int gbase = ks >> 3;
      bf16x8 af[4], bfr[4];
#pragma unroll
      for (int i = 0; i < 4; i++) {
        const int R = sub_m + 16 * i + col;
        const int slot = (gbase + quad) ^ (R & 7);
        af[i] = *(const bf16x8*)&As[R * 64 + slot * 8];
      }
#pragma unroll
      for (int j = 0; j < 4; j++) {
        const int R = sub_n + 16 * j + col;
        const int slot = (gbase + quad) ^ (R & 7);
        bfr[j] = *(const bf16x8*)&Bs[R * 64 + slot * 8];
      }
#pragma unroll
      for (int i = 0; i < 4; i++)
#pragma unroll
        for (int j = 0; j < 4; j++)
          acc[i][j] = __builtin_amdgcn_mfma_f32_16x16x32_bf16(af[i], bfr[j],
                                                              acc[i][j], 0, 0, 0);
    }
  }
}

// ---------------- core 64x128 variant (PV split-M): waves 1x4, acc 4x2 -----------
__device__ __forceinline__ void gemm_core64(
    const unsigned short* __restrict__ A,
    const unsigned short* __restrict__ B,
    int lda, int ldb, int kext,
    unsigned short* As, unsigned short* Bs,
    floatx4 acc[4][2]) {
  const int tid  = threadIdx.x;
  const int lane = tid & 63;
  const int wave = tid >> 6;
  const int sub_n = wave * 32;
  const int col  = lane & 15;
  const int quad = lane >> 4;

  const int srow  = tid >> 3;
  const int sgran = (tid & 7) ^ (srow & 7);
  const int scol  = sgran * 8;
  const int dflat = tid * 8;

  const unsigned short* Ag = A + (size_t)srow * lda + scol;
  const unsigned short* Bg = B + (size_t)srow * ldb + scol;

  for (int k0 = 0; k0 < kext; k0 += 64) {
    __syncthreads();
#pragma unroll
    for (int j = 0; j < 2; j++)
      __builtin_amdgcn_global_load_lds(
          (const __attribute__((address_space(1))) void*)(Ag + (size_t)(j * 32) * lda + k0),
          (__attribute__((address_space(3))) void*)(&As[j * 2048 + dflat]), 16, 0, 0);
#pragma unroll
    for (int j = 0; j < 4; j++)
      __builtin_amdgcn_global_load_lds(
          (const __attribute__((address_space(1))) void*)(Bg + (size_t)(j * 32) * ldb + k0),
          (__attribute__((address_space(3))) void*)(&Bs[j * 2048 + dflat]), 16, 0, 0);
    __syncthreads();
#pragma unroll
    for (int ks = 0; ks < 64; ks += 32) {
      const int gbase = ks >> 3;
      bf16x8 af[4], bfr[2];
#pragma unroll
      for (int i = 0; i < 4; i++) {
        const int R = 16 * i + col;
        const int slot = (gbase + quad) ^ (R & 7);
        af[i] = *(const bf16x8*)&As[R * 64 + slot * 8];
      }
#pragma unroll
      for (int j = 0; j < 2; j++) {
        const int R = sub_n + 16 * j + col;
        const int slot = (gbase + quad) ^ (R & 7);
        bfr[j] = *(const bf16x8*)&Bs[R * 64 + slot * 8];
      }
#pragma unroll
      for (int i = 0; i < 4; i++)
#pragma unroll
        for (int j = 0; j < 2; j++)
          acc[i][j] = __builtin_amdgcn_mfma_f32_16x16x32_bf16(af[i], bfr[j],
                                                              acc[i][j], 0, 0, 0);
    }
  }
}

// C/D layout (16x16): col = lane&15, row = quad*4 + reg   [verified m89/m91]

// ---------------- fused QKV: z=0 Q, z=1 K, z=2 V^T (= Wv x^T, coalesced) ----------
__global__ __launch_bounds__(256, 2)
void qkv_gemm(const unsigned short* __restrict__ xb,
              const unsigned short* __restrict__ wqb,
              const unsigned short* __restrict__ wkb,
              const unsigned short* __restrict__ wvb,
              const float* __restrict__ bq, const float* __restrict__ bk,
              const float* __restrict__ bv,
              unsigned short* __restrict__ qb, unsigned short* __restrict__ kb,
              unsigned short* __restrict__ vtb) {
  __shared__ unsigned short As[8192];
  __shared__ unsigned short Bs[8192];
  const int z = blockIdx.z;
  const int pid = blockIdx.x;   // 0..255

  floatx4 acc[4][4];
#pragma unroll
  for (int i = 0; i < 4; i++)
#pragma unroll
    for (int j = 0; j < 4; j++) acc[i][j] = (floatx4)0.0f;

  const int lane = threadIdx.x & 63;
  const int wave = threadIdx.x >> 6;
  const int sub_m = (wave >> 1) * 64;
  const int sub_n = (wave & 1) * 64;
  const int col  = lane & 15;
  const int quad = lane >> 4;

  if (z < 2) {
    // Q or K: [SEQ, DIM] = x[SEQ,K] * W[DIM,K]^T + b[n]
    const unsigned short* W = z ? wkb : wqb;
    const float* bias = z ? bk : bq;
    unsigned short* outp = z ? kb : qb;
    const int by = pid >> 3, bx = pid & 7;     // 8 consecutive blocks share A rows
    const int tile_m = by * 128, tile_n = bx * 128;

    gemm_core128(xb + (size_t)tile_m * DIM, W + (size_t)tile_n * DIM,
                 DIM, DIM, DIM, As, Bs, acc);

    float biasv[4];
#pragma unroll
    for (int j = 0; j < 4; j++) biasv[j] = bias[tile_n + sub_n + 16 * j + col];
#pragma unroll
    for (int i = 0; i < 4; i++)
#pragma unroll
      for (int j = 0; j < 4; j++)
#pragma unroll
        for (int r = 0; r < 4; r++) {
          const int m = tile_m + sub_m + 16 * i + quad * 4 + r;
          const int n = tile_n + sub_n + 16 * j + col;
          outp[(size_t)m * DIM + n] = f2b(acc[i][j][r] + biasv[j]);
        }
  } else {
    // V^T[DIM, SEQ] = Wv[DIM,K] * x[SEQ,K]^T + bv[m]  (row-major coalesced stores)
    const int by = pid >> 5, bx = pid & 31;
    const int tile_m = by * 128, tile_n = bx * 128;

    gemm_core128(wvb + (size_t)tile_m * DIM, xb + (size_t)tile_n * DIM,
                 DIM, DIM, DIM, As, Bs, acc);

#pragma unroll
    for (int i = 0; i < 4; i++) {
      const float* bp = &bv[tile_m + sub_m + 16 * i + quad * 4];
      float bm[4];
#pragma unroll
      for (int r = 0; r < 4; r++) bm[r] = bp[r];
#pragma unroll
      for (int j = 0; j < 4; j++)
#pragma unroll
        for (int r = 0; r < 4; r++) {
          const int m = tile_m + sub_m + 16 * i + quad * 4 + r;
          const int n = tile_n + sub_n + 16 * j + col;
          vtb[(size_t)m * SEQ + n] = f2b(acc[i][j][r] + bm[r]);
        }
    }
  }
}

// ---------------- scores = (Q K^T) * scale, bf16 out ----------------
__global__ __launch_bounds__(256, 2)
void score_gemm(const unsigned short* __restrict__ qb,
                const unsigned short* __restrict__ kb,
                unsigned short* __restrict__ sc, float scale) {
  __shared__ unsigned short As[8192];
  __shared__ unsigned short Bs[8192];
  int bx, by;
  swizzle_tiles(gridDim.x, gridDim.y, bx, by);
  const int tile_m = by * 128;
  const int tile_n = bx * 128;

  floatx4 acc[4][4];
#pragma unroll
  for (int i = 0; i < 4; i++)
#pragma unroll
    for (int j = 0; j < 4; j++) acc[i][j] = (floatx4)0.0f;

  gemm_core128(qb + (size_t)tile_m * DIM, kb + (size_t)tile_n * DIM,
               DIM, DIM, DIM, As, Bs, acc);

  const int lane = threadIdx.x & 63;
  const int wave = threadIdx.x >> 6;
  const int sub_m = (wave >> 1) * 64;
  const int sub_n = (wave & 1) * 64;
  const int col  = lane & 15;
  const int quad = lane >> 4;
#pragma unroll
  for (int i = 0; i < 4; i++)
#pragma unroll
    for (int j = 0; j < 4; j++)
#pragma unroll
      for (int r = 0; r < 4; r++) {
        const int m = tile_m + sub_m + 16 * i + quad * 4 + r;
        const int n = tile_n + sub_n + 16 * j + col;
        sc[(size_t)m * SEQ + n] = f2b(acc[i][j][r] * scale);
      }
}

// ---------------- PV split-M: 64x128 tile, full K=SEQ, fp32 out ----------------
__global__ __launch_bounds__(256, 2)
void pv_gemm(const unsigned short* __restrict__ sc,
             const unsigned short* __restrict__ vtb,
             float* __restrict__ out) {
  __shared__ unsigned short As[4096];
  __shared__ unsigned short Bs[8192];
  const int tile_m = blockIdx.y * 64;    // natural order: 8 n-blocks share A rows
  const int tile_n = blockIdx.x * 128;

  floatx4 acc[4][2];
#pragma unroll
  for (int i = 0; i < 4; i++)
#pragma unroll
    for (int j = 0; j < 2; j++) acc[i][j] = (floatx4)0.0f;

  gemm_core64(sc + (size_t)tile_m * SEQ, vtb + (size_t)tile_n * SEQ,
              SEQ, SEQ, SEQ, As, Bs, acc);

  const int lane = threadIdx.x & 63;
  const int wave = threadIdx.x >> 6;
  const int sub_n = wave * 32;
  const int col  = lane & 15;
  const int quad = lane >> 4;
#pragma unroll
  for (int i = 0; i < 4; i++)
#pragma unroll
    for (int j = 0; j < 2; j++)
#pragma unroll
      for (int r = 0; r < 4; r++) {
        const int m = tile_m + 16 * i + quad * 4 + r;
        const int n = tile_n + sub_n + 16 * j + col;
        out[(size_t)m * DIM + n] = acc[i][j][r];
      }
}

// ---------------- in-place row softmax on bf16 [SEQ, SEQ] ----------------
__global__ __launch_bounds__(256)
void softmax_inplace(unsigned short* __restrict__ P) {
  const int row = blockIdx.x;
  unsigned short* p = P + (size_t)row * SEQ;
  const int tid  = threadIdx.x;
  const int lane = tid & 63;
  const int wave = tid >> 6;

  u16x8 raw0 = *(const u16x8*)(p + tid * 16);
  u16x8 raw1 = *(const u16x8*)(p + tid * 16 + 8);
  float v[16];
#pragma unroll
  for (int k = 0; k < 8; k++) v[k] = b2f(raw0[k]);
#pragma unroll
  for (int k = 0; k < 8; k++) v[8 + k] = b2f(raw1[k]);

  float mx = -1e30f;
#pragma unroll
  for (int k = 0; k < 16; k++) mx = fmaxf(mx, v[k]);
#pragma unroll
  for (int off = 32; off > 0; off >>= 1) mx = fmaxf(mx, __shfl_xor(mx, off, 64));
  __shared__ float redm[4];
  __shared__ float reds[4];
  if (lane == 0) redm[wave] = mx;
  __syncthreads();
  mx = fmaxf(fmaxf(redm[0], redm[1]), fmaxf(redm[2], redm[3]));

  float sum = 0.0f;
#pragma unroll
  for (int k = 0; k < 16; k++) {
    v[k] = exp2f((v[k] - mx) * 1.44269504f);
    sum += v[k];
  }
#pragma unroll
  for (int off = 32; off > 0; off >>= 1) sum += __shfl_xor(sum, off, 64);
  if (lane == 0) reds[wave] = sum;
  __syncthreads();
  sum = reds[0] + reds[1] + reds[2] + reds[3];
  const float inv = 1.0f / sum;

  u16x8 o0, o1;
#pragma unroll
  for (int k = 0; k < 8; k++) o0[k] = f2b(v[k] * inv);
#pragma unroll
  for (int k = 0; k < 8; k++) o1[k] = f2b(v[8 + k] * inv);
  *(u16x8*)(p + tid * 16) = o0;
  *(u16x8*)(p + tid * 16 + 8) = o1;
}

extern "C" void kernel_launch(void* const* d_in, const int* in_sizes, int n_in,
                              void* d_out, int out_size, void* d_ws, size_t ws_size,
                              hipStream_t stream) {
  const float* x  = (const float*)d_in[0];
  const float* wq = (const float*)d_in[1];
  const float* bq = (const float*)d_in[2];
  const float* wk = (const float*)d_in[3];
  const float* bk = (const float*)d_in[4];
  const float* wv = (const float*)d_in[5];
  const float* bv = (const float*)d_in[6];

  uint8_t* ws = (uint8_t*)d_ws;
  unsigned short* xb  = (unsigned short*)(ws);                      // [0,8)   MiB
  unsigned short* wqb = (unsigned short*)(ws + ((size_t)8  << 20)); // [8,10)
  unsigned short* wkb = (unsigned short*)(ws + ((size_t)10 << 20)); // [10,12)
  unsigned short* wvb = (unsigned short*)(ws + ((size_t)12 << 20)); // [12,14)
  unsigned short* qb  = (unsigned short*)(ws + ((size_t)14 << 20)); // [14,22)
  unsigned short* kb  = (unsigned short*)(ws + ((size_t)22 << 20)); // [22,30)
  unsigned short* vtb = (unsigned short*)(ws + ((size_t)30 << 20)); // [30,38)  V^T [DIM][SEQ]
  unsigned short* sc  = (unsigned short*)(ws + ((size_t)38 << 20)); // [38,70)  scores/attn

  // fp32 -> bf16
  cvt_all<<<7168, 256, 0, stream>>>(x, wq, wk, wv, xb, wqb, wkb, wvb);

  // fused Q / K / V^T projections (768 blocks)
  qkv_gemm<<<dim3(256, 1, 3), 256, 0, stream>>>(
      xb, wqb, wkb, wvb, bq, bk, bv, qb, kb, vtb);

  // scores = (Q K^T) / sqrt(D)   (1024 blocks)
  score_gemm<<<dim3(SEQ / 128, SEQ / 128), 256, 0, stream>>>(qb, kb, sc, 0.03125f);

  // softmax rows in place
  softmax_inplace<<<SEQ, 256, 0, stream>>>(sc);

  // out = attn @ V  (split-M: 64-row tiles, 512 blocks, full K)
  pv_gemm<<<dim3(DIM / 128, SEQ / 64), 256, 0, stream>>>(sc, vtb, (float*)d_out);
}

// Round 5
// 205.571 us; speedup vs baseline: 1.0981x; 1.0889x over previous
//
#include <hip/hip_runtime.h>
#include <stdint.h>
#include <stddef.h>

#define SEQ 4096
#define DIM 1024

typedef __bf16 bf16x8 __attribute__((ext_vector_type(8)));
typedef float floatx4 __attribute__((ext_vector_type(4)));
typedef unsigned short u16x8 __attribute__((ext_vector_type(8)));

__device__ __forceinline__ unsigned short f2b(float f) {
  union { float f; unsigned u; } v; v.f = f;
  unsigned u = v.u;
  unsigned r = (u + 0x7FFFu + ((u >> 16) & 1u)) >> 16;
  return (unsigned short)r;
}
__device__ __forceinline__ float b2f(unsigned short h) {
  union { unsigned u; float f; } v; v.u = ((unsigned)h) << 16;
  return v.f;
}

// ---------------- fused fp32 -> bf16 convert (x, wq, wk, wv in one launch) --------
__global__ __launch_bounds__(256)
void cvt_all(const float* __restrict__ x, const float* __restrict__ wq,
             const float* __restrict__ wk, const float* __restrict__ wv,
             unsigned short* __restrict__ xb, unsigned short* __restrict__ wqb,
             unsigned short* __restrict__ wkb, unsigned short* __restrict__ wvb) {
  const int bid = blockIdx.x;
  const float* src;
  unsigned short* dst;
  int off;
  if (bid < 4096)      { src = x;  dst = xb;  off = bid; }
  else if (bid < 5120) { src = wq; dst = wqb; off = bid - 4096; }
  else if (bid < 6144) { src = wk; dst = wkb; off = bid - 5120; }
  else                 { src = wv; dst = wvb; off = bid - 6144; }
  const int i = off * 1024 + threadIdx.x * 4;
  float4 f = *(const float4*)(src + i);
  ushort4 o;
  o.x = f2b(f.x); o.y = f2b(f.y); o.z = f2b(f.z); o.w = f2b(f.w);
  *(ushort4*)(dst + i) = o;
}

// ---------------- supertile swizzle: 8 consecutive pids share one B-tile ----------
// Empirically (r1 vs r3 vs r4): this B-sharing M-walk cuts pv FETCH 135->49 MB;
// natural x-fastest order (A-sharing) does NOT (135 MB both times it was tried).
__device__ __forceinline__ void swizzle_tiles(int gx, int gy, int& bx, int& by) {
  const int pid = blockIdx.y * gx + blockIdx.x;
  const int GM = 8;
  const int group = pid / (GM * gx);
  const int first = group * GM;
  const int gsz = (gy - first) < GM ? (gy - first) : GM;
  by = first + (pid % gsz);
  bx = (pid % (GM * gx)) / gsz;
}

// ---------------- core 128x128 B^T-form bf16 GEMM (16x16x32 MFMA) ----------------
// C_tile[128,128] += A[0:128, :kext] * B[0:128, :kext]^T  (A,B pre-offset)
// LDS XOR-swizzle: granule g of row r at slot g^(r&7), source-column swizzled
// (global_load_lds dest is lane-ordered). Quad-rotated fragment reads measured
// conflict-free (r2/r4: SQ_LDS_BANK_CONFLICT = 0).
__device__ __forceinline__ void gemm_core128(
    const unsigned short* __restrict__ A,
    const unsigned short* __restrict__ B,
    int lda, int ldb, int kext,
    unsigned short* As, unsigned short* Bs,
    floatx4 acc[4][4]) {
  const int tid  = threadIdx.x;
  const int lane = tid & 63;
  const int wave = tid >> 6;
  const int sub_m = (wave >> 1) * 64;
  const int sub_n = (wave & 1) * 64;
  const int col  = lane & 15;
  const int quad = lane >> 4;

  const int srow  = tid >> 3;
  const int sgran = (tid & 7) ^ (srow & 7);
  const int scol  = sgran * 8;
  const int dflat = tid * 8;

  const unsigned short* Ag = A + (size_t)srow * lda + scol;
  const unsigned short* Bg = B + (size_t)srow * ldb + scol;

  for (int k0 = 0; k0 < kext; k0 += 64) {
    __syncthreads();
#pragma unroll
    for (int j = 0; j < 4; j++) {
      __builtin_amdgcn_global_load_lds(
          (const __attribute__((address_space(1))) void*)(Ag + (size_t)(j * 32) * lda + k0),
          (__attribute__((address_space(3))) void*)(&As[j * 2048 + dflat]), 16, 0, 0);
      __builtin_amdgcn_global_load_lds(
          (const __attribute__((address_space(1))) void*)(Bg + (size_t)(j * 32) * ldb + k0),
          (__attribute__((address_space(3))) void*)(&Bs[j * 2048 + dflat]), 16, 0, 0);
    }
    __syncthreads();
#pragma unroll
    for (int ks = 0; ks < 64; ks += 32) {
      const int gbase = ks >> 3;
      bf16x8 af[4], bfr[4];
#pragma unroll
      for (int i = 0; i < 4; i++) {
        const int R = sub_m + 16 * i + col;
        const int slot = (gbase + quad) ^ (R & 7);
        af[i] = *(const bf16x8*)&As[R * 64 + slot * 8];
      }
#pragma unroll
      for (int j = 0; j < 4; j++) {
        const int R = sub_n + 16 * j + col;
        const int slot = (gbase + quad) ^ (R & 7);
        bfr[j] = *(const bf16x8*)&Bs[R * 64 + slot * 8];
      }
#pragma unroll
      for (int i = 0; i < 4; i++)
#pragma unroll
        for (int j = 0; j < 4; j++)
          acc[i][j] = __builtin_amdgcn_mfma_f32_16x16x32_bf16(af[i], bfr[j],
                                                              acc[i][j], 0, 0, 0);
    }
  }
}

// C/D layout (16x16): col = lane&15, row = quad*4 + reg   [verified m89/m91]

// ---------------- fused QKV: z=0 Q, z=1 K, z=2 V^T (= Wv x^T, coalesced) ----------
__global__ __launch_bounds__(256, 2)
void qkv_gemm(const unsigned short* __restrict__ xb,
              const unsigned short* __restrict__ wqb,
              const unsigned short* __restrict__ wkb,
              const unsigned short* __restrict__ wvb,
              const float* __restrict__ bq, const float* __restrict__ bk,
              const float* __restrict__ bv,
              unsigned short* __restrict__ qb, unsigned short* __restrict__ kb,
              unsigned short* __restrict__ vtb) {
  __shared__ unsigned short As[8192];
  __shared__ unsigned short Bs[8192];
  const int z = blockIdx.z;
  const int pid = blockIdx.x;   // 0..255

  floatx4 acc[4][4];
#pragma unroll
  for (int i = 0; i < 4; i++)
#pragma unroll
    for (int j = 0; j < 4; j++) acc[i][j] = (floatx4)0.0f;

  const int lane = threadIdx.x & 63;
  const int wave = threadIdx.x >> 6;
  const int sub_m = (wave >> 1) * 64;
  const int sub_n = (wave & 1) * 64;
  const int col  = lane & 15;
  const int quad = lane >> 4;

  if (z < 2) {
    // Q or K: [SEQ, DIM] = x[SEQ,K] * W[DIM,K]^T + b[n]
    const unsigned short* W = z ? wkb : wqb;
    const float* bias = z ? bk : bq;
    unsigned short* outp = z ? kb : qb;
    const int by = pid >> 3, bx = pid & 7;
    const int tile_m = by * 128, tile_n = bx * 128;

    gemm_core128(xb + (size_t)tile_m * DIM, W + (size_t)tile_n * DIM,
                 DIM, DIM, DIM, As, Bs, acc);

    float biasv[4];
#pragma unroll
    for (int j = 0; j < 4; j++) biasv[j] = bias[tile_n + sub_n + 16 * j + col];
#pragma unroll
    for (int i = 0; i < 4; i++)
#pragma unroll
      for (int j = 0; j < 4; j++)
#pragma unroll
        for (int r = 0; r < 4; r++) {
          const int m = tile_m + sub_m + 16 * i + quad * 4 + r;
          const int n = tile_n + sub_n + 16 * j + col;
          outp[(size_t)m * DIM + n] = f2b(acc[i][j][r] + biasv[j]);
        }
  } else {
    // V^T[DIM, SEQ] = Wv[DIM,K] * x[SEQ,K]^T + bv[m]  (row-major coalesced stores)
    const int by = pid >> 5, bx = pid & 31;
    const int tile_m = by * 128, tile_n = bx * 128;

    gemm_core128(wvb + (size_t)tile_m * DIM, xb + (size_t)tile_n * DIM,
                 DIM, DIM, DIM, As, Bs, acc);

#pragma unroll
    for (int i = 0; i < 4; i++) {
      const float* bp = &bv[tile_m + sub_m + 16 * i + quad * 4];
      float bm[4];
#pragma unroll
      for (int r = 0; r < 4; r++) bm[r] = bp[r];
#pragma unroll
      for (int j = 0; j < 4; j++)
#pragma unroll
        for (int r = 0; r < 4; r++) {
          const int m = tile_m + sub_m + 16 * i + quad * 4 + r;
          const int n = tile_n + sub_n + 16 * j + col;
          vtb[(size_t)m * SEQ + n] = f2b(acc[i][j][r] + bm[r]);
        }
    }
  }
}

// ---------------- scores = (Q K^T) * scale, bf16 out ----------------
// XCD-banded tile map: assuming round-robin pid->XCD, each XCD owns a 4-wide
// N-band (its 1 MB of K-tiles stays hot in its private 4 MiB L2) and walks M;
// Q streams in the same order on all XCDs -> served by shared L3.
__global__ __launch_bounds__(256, 2)
void score_gemm(const unsigned short* __restrict__ qb,
                const unsigned short* __restrict__ kb,
                unsigned short* __restrict__ sc, float scale) {
  __shared__ unsigned short As[8192];
  __shared__ unsigned short Bs[8192];
  const int pid = blockIdx.y * gridDim.x + blockIdx.x;
  const int xcd = pid & 7;
  const int local = pid >> 3;            // 0..127
  const int bx = xcd * 4 + (local & 3);  // N-tile pinned to XCD band
  const int by = local >> 2;             // 0..31
  const int tile_m = by * 128;
  const int tile_n = bx * 128;

  floatx4 acc[4][4];
#pragma unroll
  for (int i = 0; i < 4; i++)
#pragma unroll
    for (int j = 0; j < 4; j++) acc[i][j] = (floatx4)0.0f;

  gemm_core128(qb + (size_t)tile_m * DIM, kb + (size_t)tile_n * DIM,
               DIM, DIM, DIM, As, Bs, acc);

  const int lane = threadIdx.x & 63;
  const int wave = threadIdx.x >> 6;
  const int sub_m = (wave >> 1) * 64;
  const int sub_n = (wave & 1) * 64;
  const int col  = lane & 15;
  const int quad = lane >> 4;
#pragma unroll
  for (int i = 0; i < 4; i++)
#pragma unroll
    for (int j = 0; j < 4; j++)
#pragma unroll
      for (int r = 0; r < 4; r++) {
        const int m = tile_m + sub_m + 16 * i + quad * 4 + r;
        const int n = tile_n + sub_n + 16 * j + col;
        sc[(size_t)m * SEQ + n] = f2b(acc[i][j][r] * scale);
      }
}

// ---------------- PV split-K=2: z=0 -> d_out, z=1 -> partial ----------------
__global__ __launch_bounds__(256, 2)
void pv_gemm(const unsigned short* __restrict__ sc,
             const unsigned short* __restrict__ vtb,
             float* __restrict__ out0, float* __restrict__ out1) {
  __shared__ unsigned short As[8192];
  __shared__ unsigned short Bs[8192];
  const int z = blockIdx.z;
  const int koff = z * (SEQ / 2);
  float* C = z ? out1 : out0;
  int bx, by;
  swizzle_tiles(gridDim.x, gridDim.y, bx, by);
  const int tile_m = by * 128;
  const int tile_n = bx * 128;

  floatx4 acc[4][4];
#pragma unroll
  for (int i = 0; i < 4; i++)
#pragma unroll
    for (int j = 0; j < 4; j++) acc[i][j] = (floatx4)0.0f;

  gemm_core128(sc + (size_t)tile_m * SEQ + koff,
               vtb + (size_t)tile_n * SEQ + koff,
               SEQ, SEQ, SEQ / 2, As, Bs, acc);

  const int lane = threadIdx.x & 63;
  const int wave = threadIdx.x >> 6;
  const int sub_m = (wave >> 1) * 64;
  const int sub_n = (wave & 1) * 64;
  const int col  = lane & 15;
  const int quad = lane >> 4;
#pragma unroll
  for (int i = 0; i < 4; i++)
#pragma unroll
    for (int j = 0; j < 4; j++)
#pragma unroll
      for (int r = 0; r < 4; r++) {
        const int m = tile_m + sub_m + 16 * i + quad * 4 + r;
        const int n = tile_n + sub_n + 16 * j + col;
        C[(size_t)m * DIM + n] = acc[i][j][r];
      }
}

// ---------------- out += partial ----------------
__global__ __launch_bounds__(256)
void reduce_add(float* __restrict__ out, const float* __restrict__ part) {
  const int i = (blockIdx.x * 256 + threadIdx.x) * 4;
  float4 a = *(const float4*)(out + i);
  float4 b = *(const float4*)(part + i);
  a.x += b.x; a.y += b.y; a.z += b.z; a.w += b.w;
  *(float4*)(out + i) = a;
}

// ---------------- in-place row softmax on bf16 [SEQ, SEQ] ----------------
__global__ __launch_bounds__(256)
void softmax_inplace(unsigned short* __restrict__ P) {
  const int row = blockIdx.x;
  unsigned short* p = P + (size_t)row * SEQ;
  const int tid  = threadIdx.x;
  const int lane = tid & 63;
  const int wave = tid >> 6;

  u16x8 raw0 = *(const u16x8*)(p + tid * 16);
  u16x8 raw1 = *(const u16x8*)(p + tid * 16 + 8);
  float v[16];
#pragma unroll
  for (int k = 0; k < 8; k++) v[k] = b2f(raw0[k]);
#pragma unroll
  for (int k = 0; k < 8; k++) v[8 + k] = b2f(raw1[k]);

  float mx = -1e30f;
#pragma unroll
  for (int k = 0; k < 16; k++) mx = fmaxf(mx, v[k]);
#pragma unroll
  for (int off = 32; off > 0; off >>= 1) mx = fmaxf(mx, __shfl_xor(mx, off, 64));
  __shared__ float redm[4];
  __shared__ float reds[4];
  if (lane == 0) redm[wave] = mx;
  __syncthreads();
  mx = fmaxf(fmaxf(redm[0], redm[1]), fmaxf(redm[2], redm[3]));

  float sum = 0.0f;
#pragma unroll
  for (int k = 0; k < 16; k++) {
    v[k] = exp2f((v[k] - mx) * 1.44269504f);
    sum += v[k];
  }
#pragma unroll
  for (int off = 32; off > 0; off >>= 1) sum += __shfl_xor(sum, off, 64);
  if (lane == 0) reds[wave] = sum;
  __syncthreads();
  sum = reds[0] + reds[1] + reds[2] + reds[3];
  const float inv = 1.0f / sum;

  u16x8 o0, o1;
#pragma unroll
  for (int k = 0; k < 8; k++) o0[k] = f2b(v[k] * inv);
#pragma unroll
  for (int k = 0; k < 8; k++) o1[k] = f2b(v[8 + k] * inv);
  *(u16x8*)(p + tid * 16) = o0;
  *(u16x8*)(p + tid * 16 + 8) = o1;
}

extern "C" void kernel_launch(void* const* d_in, const int* in_sizes, int n_in,
                              void* d_out, int out_size, void* d_ws, size_t ws_size,
                              hipStream_t stream) {
  const float* x  = (const float*)d_in[0];
  const float* wq = (const float*)d_in[1];
  const float* bq = (const float*)d_in[2];
  const float* wk = (const float*)d_in[3];
  const float* bk = (const float*)d_in[4];
  const float* wv = (const float*)d_in[5];
  const float* bv = (const float*)d_in[6];

  uint8_t* ws = (uint8_t*)d_ws;
  unsigned short* xb  = (unsigned short*)(ws);                      // [0,8)   MiB
  unsigned short* wqb = (unsigned short*)(ws + ((size_t)8  << 20)); // [8,10)
  unsigned short* wkb = (unsigned short*)(ws + ((size_t)10 << 20)); // [10,12)
  unsigned short* wvb = (unsigned short*)(ws + ((size_t)12 << 20)); // [12,14)
  unsigned short* qb  = (unsigned short*)(ws + ((size_t)14 << 20)); // [14,22)
  unsigned short* kb  = (unsigned short*)(ws + ((size_t)22 << 20)); // [22,30)
  unsigned short* vtb = (unsigned short*)(ws + ((size_t)30 << 20)); // [30,38)  V^T [DIM][SEQ]
  unsigned short* sc  = (unsigned short*)(ws + ((size_t)38 << 20)); // [38,70)  scores/attn
  float*          part = (float*)(ws);                              // [0,16)   PV partial (xb/w* dead by then)

  // fp32 -> bf16
  cvt_all<<<7168, 256, 0, stream>>>(x, wq, wk, wv, xb, wqb, wkb, wvb);

  // fused Q / K / V^T projections (768 blocks)
  qkv_gemm<<<dim3(256, 1, 3), 256, 0, stream>>>(
      xb, wqb, wkb, wvb, bq, bk, bv, qb, kb, vtb);

  // scores = (Q K^T) / sqrt(D)   (1024 blocks, XCD-banded)
  score_gemm<<<dim3(SEQ / 128, SEQ / 128), 256, 0, stream>>>(qb, kb, sc, 0.03125f);

  // softmax rows in place
  softmax_inplace<<<SEQ, 256, 0, stream>>>(sc);

  // out = attn @ V, split-K=2 (512 blocks): chunk0 -> d_out, chunk1 -> part
  pv_gemm<<<dim3(DIM / 128, SEQ / 128, 2), 256, 0, stream>>>(
      sc, vtb, (float*)d_out, part);

  // d_out += part
  reduce_add<<<(SEQ * DIM) / 1024, 256, 0, stream>>>((float*)d_out, part);
}